// Round 3
// baseline (419.279 us; speedup 1.0000x reference)
//
#include <hip/hip_runtime.h>
#include <hip/hip_bf16.h>

// MoEProcessor: B=4,S=2048 -> T=8192 tokens, D=1024, E=8, K=2.
// Inputs/outputs are FLOAT32 (reference dtypes); internal GEMM compute is bf16 MFMA
// (threshold is 2% of max|ref| = 4.75e-2, ample for bf16 dots at D=1024).
// Pipeline: zero counts -> transpose+cast W_exp -> routing fp32 (per-(slot,expert)
// lists) -> grouped GEMM slot0 (write out) -> grouped GEMM slot1 (accumulate).

typedef unsigned short u16;
typedef __bf16 bf16x8 __attribute__((ext_vector_type(8)));
typedef float floatx4 __attribute__((ext_vector_type(4)));
typedef unsigned short u16x8 __attribute__((ext_vector_type(8)));

#define NTOK 8192
#define DDIM 1024
#define NEXP 8

__device__ __forceinline__ u16 f2bf(float f) {
    union { float f; unsigned int i; } c; c.f = f;
    unsigned int i = c.i;
    return (u16)((i + 0x7fffu + ((i >> 16) & 1u)) >> 16);
}
__device__ __forceinline__ float bf2f(u16 u) {
    union { unsigned int i; float f; } c; c.i = ((unsigned int)u) << 16; return c.f;
}

// ---------------- zero the 16 (slot,expert) counters ----------------
__global__ void zero_counts(int* __restrict__ c) {
    if (threadIdx.x < 16) c[threadIdx.x] = 0;
}

// -------- W_exp transpose+cast: WT[e][f][d] = bf16(W[e][d][f]) (fp32 in) --------
__global__ __launch_bounds__(256) void transpose_w(const float* __restrict__ W,
                                                   u16* __restrict__ WT) {
    __shared__ __align__(16) u16 tile[64][72];
    const int e = blockIdx.z, d0 = blockIdx.y * 64, f0 = blockIdx.x * 64;
    const int t = threadIdx.x;
    const float* src = W + (size_t)e * DDIM * DDIM;
    u16* dst = WT + (size_t)e * DDIM * DDIM;
#pragma unroll
    for (int it = 0; it < 2; ++it) {
        int idx = it * 256 + t;
        int r = idx >> 3, c8 = idx & 7;
        const float* sp = src + (size_t)(d0 + r) * DDIM + f0 + c8 * 8;
        float4 va = *(const float4*)sp;
        float4 vb = *(const float4*)(sp + 4);
        u16x8 v;
        v[0] = f2bf(va.x); v[1] = f2bf(va.y); v[2] = f2bf(va.z); v[3] = f2bf(va.w);
        v[4] = f2bf(vb.x); v[5] = f2bf(vb.y); v[6] = f2bf(vb.z); v[7] = f2bf(vb.w);
        *(u16x8*)&tile[r][c8 * 8] = v;
    }
    __syncthreads();
#pragma unroll
    for (int it = 0; it < 2; ++it) {
        int idx = it * 256 + t;
        int fr = idx >> 3, d8 = idx & 7;
        u16x8 o;
#pragma unroll
        for (int j = 0; j < 8; ++j) o[j] = tile[d8 * 8 + j][fr];
        *(u16x8*)(dst + (size_t)(f0 + fr) * DDIM + d0 + d8 * 8) = o;
    }
}

// -------- routing (all fp32): logits -> LN -> softmax -> +noise -> top2 --------
__global__ __launch_bounds__(256) void routing_kernel(
    const float* __restrict__ x, const float* __restrict__ noise,
    const float* __restrict__ Wr, const float* __restrict__ br,
    const float* __restrict__ gamma, const float* __restrict__ beta,
    int* __restrict__ counts, int* __restrict__ list_tok, float* __restrict__ list_w) {
    __shared__ __align__(16) float wr_s[DDIM * NEXP]; // 32 KiB
    const int t = threadIdx.x;
#pragma unroll
    for (int i = 0; i < 8; ++i)
        *(float4*)&wr_s[t * 32 + i * 4] = *(const float4*)&Wr[t * 32 + i * 4];
    __syncthreads();

    const int wave = t >> 6, lane = t & 63;
    const int tok = blockIdx.x * 4 + wave;
    const float* xrow = x + (size_t)tok * DDIM;

    float acc[8];
#pragma unroll
    for (int e = 0; e < 8; ++e) acc[e] = 0.f;
#pragma unroll
    for (int i = 0; i < 16; ++i) {
        int d = i * 64 + lane;
        float xd = xrow[d];
#pragma unroll
        for (int e = 0; e < 8; ++e) acc[e] += xd * wr_s[d * 8 + e];
    }
#pragma unroll
    for (int off = 32; off >= 1; off >>= 1) {
#pragma unroll
        for (int e = 0; e < 8; ++e) acc[e] += __shfl_xor(acc[e], off, 64);
    }
    if (lane == 0) {
        float lg[8], mu = 0.f;
#pragma unroll
        for (int e = 0; e < 8; ++e) { lg[e] = acc[e] + br[e]; mu += lg[e]; }
        mu *= 0.125f;
        float var = 0.f;
#pragma unroll
        for (int e = 0; e < 8; ++e) { float d = lg[e] - mu; var += d * d; }
        var *= 0.125f;
        float rstd = rsqrtf(var + 1e-5f);
        float ln[8], mx = -1e30f;
#pragma unroll
        for (int e = 0; e < 8; ++e) {
            ln[e] = (lg[e] - mu) * rstd * gamma[e] + beta[e];
            mx = fmaxf(mx, ln[e]);
        }
        float s = 0.f, p[8];
#pragma unroll
        for (int e = 0; e < 8; ++e) { p[e] = expf(ln[e] - mx); s += p[e]; }
        float inv = 1.f / s, r[8];
#pragma unroll
        for (int e = 0; e < 8; ++e) r[e] = p[e] * inv + noise[(size_t)tok * 8 + e];
        // top-2, ties -> lower index (matches jax.lax.top_k)
        int i0 = 0; float v0 = r[0];
#pragma unroll
        for (int e = 1; e < 8; ++e) if (r[e] > v0) { v0 = r[e]; i0 = e; }
        int i1 = -1; float v1 = -1e30f;
#pragma unroll
        for (int e = 0; e < 8; ++e) if (e != i0 && r[e] > v1) { v1 = r[e]; i1 = e; }
        float w0 = 1.f / (1.f + expf(v1 - v0));
        float w1 = 1.f - w0;
        int p0 = atomicAdd(&counts[i0], 1);          // slot0 group = expert i0
        list_tok[i0 * NTOK + p0] = tok; list_w[i0 * NTOK + p0] = w0;
        int p1 = atomicAdd(&counts[8 + i1], 1);      // slot1 group = 8 + expert i1
        list_tok[(8 + i1) * NTOK + p1] = tok; list_w[(8 + i1) * NTOK + p1] = w1;
    }
}

// ------- grouped expert GEMM: out[tok] (+)= w*(bf16(x)@WT_e + b_e), fp32 out -------
__global__ __launch_bounds__(256) void moe_gemm(
    const float* __restrict__ x, const u16* __restrict__ WT,
    const float* __restrict__ bexp, const int* __restrict__ counts,
    const int* __restrict__ list_tok, const float* __restrict__ list_w,
    float* __restrict__ out, int grp_base, int accum) {
    const int e = blockIdx.z;
    const int grp = grp_base + e;
    int cnt = counts[grp];
    cnt = cnt < 0 ? 0 : (cnt > NTOK ? NTOK : cnt);   // defensive
    const int m0 = blockIdx.y * 128;
    if (m0 >= cnt) return;
    const int n0 = blockIdx.x * 128;

    __shared__ __align__(16) u16 A_s[128 * 32]; // [row][k], 8 KiB bf16
    __shared__ __align__(16) u16 B_s[128 * 32]; // [n][k],   8 KiB bf16 (from WT)
    __shared__ int tok_s[128];
    __shared__ float w_s[128];
    __shared__ float bias_s[128];

    const int t = threadIdx.x;
    if (t < 128) {
        int r = m0 + t;
        int rr = r < cnt ? r : cnt - 1;
        tok_s[t] = list_tok[grp * NTOK + rr] & (NTOK - 1);  // defensive clamp
        w_s[t] = (r < cnt) ? list_w[grp * NTOK + rr] : 0.f;
        bias_s[t] = bexp[e * DDIM + n0 + t];
    }
    __syncthreads();

    const int ra = t >> 2;          // staging row 0..63
    const int co = (t & 3) * 8;     // element offset within 32-elem k-chunk
    const float* xg0 = x + (size_t)tok_s[ra] * DDIM + co;
    const float* xg1 = x + (size_t)tok_s[64 + ra] * DDIM + co;
    const u16* wg0 = WT + ((size_t)e * DDIM + n0 + ra) * DDIM + co;
    const u16* wg1 = WT + ((size_t)e * DDIM + n0 + 64 + ra) * DDIM + co;
    u16* sA0 = A_s + ra * 32 + co;          // = A_s + t*8: conflict-free b128 writes
    u16* sA1 = A_s + (64 + ra) * 32 + co;
    u16* sB0 = B_s + ra * 32 + co;
    u16* sB1 = B_s + (64 + ra) * 32 + co;

    const int lane = t & 63, wave = t >> 6;
    const int wm = wave >> 1, wn = wave & 1;
    const int lm = lane & 15;
    const int ko = (lane >> 4) * 8;

    floatx4 acc[4][4];
#pragma unroll
    for (int mi = 0; mi < 4; ++mi)
#pragma unroll
        for (int ni = 0; ni < 4; ++ni) acc[mi][ni] = (floatx4){0.f, 0.f, 0.f, 0.f};

    for (int kk = 0; kk < DDIM; kk += 32) {
        float4 fa0 = *(const float4*)(xg0 + kk);
        float4 fa0b = *(const float4*)(xg0 + kk + 4);
        float4 fa1 = *(const float4*)(xg1 + kk);
        float4 fa1b = *(const float4*)(xg1 + kk + 4);
        u16x8 b0 = *(const u16x8*)(wg0 + kk);
        u16x8 b1 = *(const u16x8*)(wg1 + kk);
        u16x8 a0, a1;
        a0[0] = f2bf(fa0.x); a0[1] = f2bf(fa0.y); a0[2] = f2bf(fa0.z); a0[3] = f2bf(fa0.w);
        a0[4] = f2bf(fa0b.x); a0[5] = f2bf(fa0b.y); a0[6] = f2bf(fa0b.z); a0[7] = f2bf(fa0b.w);
        a1[0] = f2bf(fa1.x); a1[1] = f2bf(fa1.y); a1[2] = f2bf(fa1.z); a1[3] = f2bf(fa1.w);
        a1[4] = f2bf(fa1b.x); a1[5] = f2bf(fa1b.y); a1[6] = f2bf(fa1b.z); a1[7] = f2bf(fa1b.w);
        __syncthreads();            // prior iter's ds_reads done before overwrite
        *(u16x8*)sA0 = a0;
        *(u16x8*)sA1 = a1;
        *(u16x8*)sB0 = b0;
        *(u16x8*)sB1 = b1;
        __syncthreads();            // LDS writes visible
        bf16x8 af[4], bfr[4];
#pragma unroll
        for (int mi = 0; mi < 4; ++mi)
            af[mi] = *(const bf16x8*)&A_s[(wm * 64 + mi * 16 + lm) * 32 + ko];
#pragma unroll
        for (int ni = 0; ni < 4; ++ni)
            bfr[ni] = *(const bf16x8*)&B_s[(wn * 64 + ni * 16 + lm) * 32 + ko];
#pragma unroll
        for (int mi = 0; mi < 4; ++mi)
#pragma unroll
            for (int ni = 0; ni < 4; ++ni)
                acc[mi][ni] = __builtin_amdgcn_mfma_f32_16x16x32_bf16(
                    af[mi], bfr[ni], acc[mi][ni], 0, 0, 0);
    }

    // epilogue: C row = (lane>>4)*4+reg, col = lane&15 within each 16x16 tile
#pragma unroll
    for (int mi = 0; mi < 4; ++mi) {
        int rb = wm * 64 + mi * 16 + (lane >> 4) * 4;
#pragma unroll
        for (int reg = 0; reg < 4; ++reg) {
            int r = rb + reg;
            if (m0 + r < cnt) {
                size_t tok = (size_t)tok_s[r];
                float w = w_s[r];
                float* yrow = out + tok * DDIM + n0;
#pragma unroll
                for (int ni = 0; ni < 4; ++ni) {
                    int col = wn * 64 + ni * 16 + lm;
                    float v = w * (acc[mi][ni][reg] + bias_s[col]);
                    if (accum) v += yrow[col];
                    yrow[col] = v;
                }
            }
        }
    }
}

extern "C" void kernel_launch(void* const* d_in, const int* in_sizes, int n_in,
                              void* d_out, int out_size, void* d_ws, size_t ws_size,
                              hipStream_t stream) {
    const float* x     = (const float*)d_in[0];
    const float* noise = (const float*)d_in[1];
    const float* Wr    = (const float*)d_in[2];
    const float* br    = (const float*)d_in[3];
    const float* gamma = (const float*)d_in[4];
    const float* beta  = (const float*)d_in[5];
    const float* Wexp  = (const float*)d_in[6];
    const float* bexp  = (const float*)d_in[7];
    float* out = (float*)d_out;

    unsigned char* ws = (unsigned char*)d_ws;
    u16* WT       = (u16*)ws;                              // 16 MiB: WT[E][F][D] bf16
    int* counts   = (int*)(ws + 16777216);                 // 64 B (16 ints)
    int* list_tok = (int*)(ws + 16777216 + 256);           // 512 KiB: [16][NTOK]
    float* list_w = (float*)(ws + 16777216 + 256 + 524288);// 512 KiB
    // total ws use: ~17.8 MiB (same footprint as round 2, known in-bounds)

    zero_counts<<<1, 64, 0, stream>>>(counts);
    transpose_w<<<dim3(16, 16, 8), 256, 0, stream>>>(Wexp, WT);
    routing_kernel<<<NTOK / 4, 256, 0, stream>>>(x, noise, Wr, br, gamma, beta,
                                                 counts, list_tok, list_w);
    moe_gemm<<<dim3(8, 64, 8), 256, 0, stream>>>(x, WT, bexp, counts, list_tok, list_w,
                                                 out, 0, 0);  // slot0: write
    moe_gemm<<<dim3(8, 64, 8), 256, 0, stream>>>(x, WT, bexp, counts, list_tok, list_w,
                                                 out, 8, 1);  // slot1: accumulate
}

// Round 4
// 416.656 us; speedup vs baseline: 1.0063x; 1.0063x over previous
//
#include <hip/hip_runtime.h>
#include <hip/hip_bf16.h>

// MoEProcessor: B=4,S=2048 -> T=8192 tokens, D=1024, E=8, K=2. fp32 in/out.
// Internal GEMM compute bf16 MFMA. Round 4: routing rewritten conflict-free
// (was 196us with 4.7M LDS bank conflicts); GEMM path unchanged (known correct).

typedef unsigned short u16;
typedef __bf16 bf16x8 __attribute__((ext_vector_type(8)));
typedef float floatx4 __attribute__((ext_vector_type(4)));
typedef unsigned short u16x8 __attribute__((ext_vector_type(8)));

#define NTOK 8192
#define DDIM 1024
#define NEXP 8

__device__ __forceinline__ u16 f2bf(float f) {
    union { float f; unsigned int i; } c; c.f = f;
    unsigned int i = c.i;
    return (u16)((i + 0x7fffu + ((i >> 16) & 1u)) >> 16);
}

// ---------------- zero the 16 (slot,expert) counters ----------------
__global__ void zero_counts(int* __restrict__ c) {
    if (threadIdx.x < 16) c[threadIdx.x] = 0;
}

// -------- W_exp transpose+cast: WT[e][f][d] = bf16(W[e][d][f]) (fp32 in) --------
__global__ __launch_bounds__(256) void transpose_w(const float* __restrict__ W,
                                                   u16* __restrict__ WT) {
    __shared__ __align__(16) u16 tile[64][72];
    const int e = blockIdx.z, d0 = blockIdx.y * 64, f0 = blockIdx.x * 64;
    const int t = threadIdx.x;
    const float* src = W + (size_t)e * DDIM * DDIM;
    u16* dst = WT + (size_t)e * DDIM * DDIM;
#pragma unroll
    for (int it = 0; it < 2; ++it) {
        int idx = it * 256 + t;
        int r = idx >> 3, c8 = idx & 7;
        const float* sp = src + (size_t)(d0 + r) * DDIM + f0 + c8 * 8;
        float4 va = *(const float4*)sp;
        float4 vb = *(const float4*)(sp + 4);
        u16x8 v;
        v[0] = f2bf(va.x); v[1] = f2bf(va.y); v[2] = f2bf(va.z); v[3] = f2bf(va.w);
        v[4] = f2bf(vb.x); v[5] = f2bf(vb.y); v[6] = f2bf(vb.z); v[7] = f2bf(vb.w);
        *(u16x8*)&tile[r][c8 * 8] = v;
    }
    __syncthreads();
#pragma unroll
    for (int it = 0; it < 2; ++it) {
        int idx = it * 256 + t;
        int fr = idx >> 3, d8 = idx & 7;
        u16x8 o;
#pragma unroll
        for (int j = 0; j < 8; ++j) o[j] = tile[d8 * 8 + j][fr];
        *(u16x8*)(dst + (size_t)(f0 + fr) * DDIM + d0 + d8 * 8) = o;
    }
}

// -------- routing v2 (fp32, conflict-free LDS): one wave per token, 8 tok/wave ----
__global__ __launch_bounds__(256) void routing_kernel(
    const float* __restrict__ x, const float* __restrict__ noise,
    const float* __restrict__ Wr, const float* __restrict__ br,
    const float* __restrict__ gamma, const float* __restrict__ beta,
    int* __restrict__ counts, int* __restrict__ list_tok, float* __restrict__ list_w) {
    __shared__ __align__(16) float wrT[NEXP][DDIM]; // 32 KiB, transposed
    const int t = threadIdx.x;
    // Load+transpose Wr[d][e] -> wrT[e][d]. Write pattern: per j, 2 lanes/bank (free).
#pragma unroll
    for (int i = 0; i < 8; ++i) {
        int f4 = i * 256 + t;            // float4 index 0..2047 over D*E floats
        int d = f4 >> 1, half = (f4 & 1) * 4;
        float4 v = *(const float4*)&Wr[d * 8 + half];
        wrT[half + 0][d] = v.x; wrT[half + 1][d] = v.y;
        wrT[half + 2][d] = v.z; wrT[half + 3][d] = v.w;
    }
    __syncthreads();

    const int wave = t >> 6, lane = t & 63;
    for (int it = 0; it < 8; ++it) {
        const int tok = blockIdx.x * 32 + wave * 8 + it;
        const float4* xrow = (const float4*)(x + (size_t)tok * DDIM);
        float acc[8];
#pragma unroll
        for (int e = 0; e < 8; ++e) acc[e] = 0.f;
#pragma unroll
        for (int i = 0; i < 4; ++i) {
            int d4 = i * 64 + lane;      // float4 index within row; lanes 16B-contig
            float4 xv = xrow[d4];
#pragma unroll
            for (int e = 0; e < 8; ++e) {
                float4 wv = *(const float4*)&wrT[e][d4 * 4];
                acc[e] += xv.x * wv.x + xv.y * wv.y + xv.z * wv.z + xv.w * wv.w;
            }
        }
#pragma unroll
        for (int off = 32; off >= 1; off >>= 1) {
#pragma unroll
            for (int e = 0; e < 8; ++e) acc[e] += __shfl_xor(acc[e], off, 64);
        }
        if (lane == 0) {
            float lg[8], mu = 0.f;
#pragma unroll
            for (int e = 0; e < 8; ++e) { lg[e] = acc[e] + br[e]; mu += lg[e]; }
            mu *= 0.125f;
            float var = 0.f;
#pragma unroll
            for (int e = 0; e < 8; ++e) { float d = lg[e] - mu; var += d * d; }
            var *= 0.125f;
            float rstd = rsqrtf(var + 1e-5f);
            float ln[8], mx = -1e30f;
#pragma unroll
            for (int e = 0; e < 8; ++e) {
                ln[e] = (lg[e] - mu) * rstd * gamma[e] + beta[e];
                mx = fmaxf(mx, ln[e]);
            }
            float s = 0.f, p[8];
#pragma unroll
            for (int e = 0; e < 8; ++e) { p[e] = expf(ln[e] - mx); s += p[e]; }
            float inv = 1.f / s, r[8];
#pragma unroll
            for (int e = 0; e < 8; ++e) r[e] = p[e] * inv + noise[(size_t)tok * 8 + e];
            // top-2, ties -> lower index (matches jax.lax.top_k)
            int i0 = 0; float v0 = r[0];
#pragma unroll
            for (int e = 1; e < 8; ++e) if (r[e] > v0) { v0 = r[e]; i0 = e; }
            int i1 = -1; float v1 = -1e30f;
#pragma unroll
            for (int e = 0; e < 8; ++e) if (e != i0 && r[e] > v1) { v1 = r[e]; i1 = e; }
            float w0 = 1.f / (1.f + expf(v1 - v0));
            float w1 = 1.f - w0;
            int p0 = atomicAdd(&counts[i0], 1);          // slot0 group = expert i0
            list_tok[i0 * NTOK + p0] = tok; list_w[i0 * NTOK + p0] = w0;
            int p1 = atomicAdd(&counts[8 + i1], 1);      // slot1 group = 8 + expert i1
            list_tok[(8 + i1) * NTOK + p1] = tok; list_w[(8 + i1) * NTOK + p1] = w1;
        }
    }
}

// ------- grouped expert GEMM: out[tok] (+)= w*(bf16(x)@WT_e + b_e), fp32 out -------
__global__ __launch_bounds__(256) void moe_gemm(
    const float* __restrict__ x, const u16* __restrict__ WT,
    const float* __restrict__ bexp, const int* __restrict__ counts,
    const int* __restrict__ list_tok, const float* __restrict__ list_w,
    float* __restrict__ out, int grp_base, int accum) {
    const int e = blockIdx.z;
    const int grp = grp_base + e;
    int cnt = counts[grp];
    cnt = cnt < 0 ? 0 : (cnt > NTOK ? NTOK : cnt);   // defensive
    const int m0 = blockIdx.y * 128;
    if (m0 >= cnt) return;
    const int n0 = blockIdx.x * 128;

    __shared__ __align__(16) u16 A_s[128 * 32]; // [row][k], 8 KiB bf16
    __shared__ __align__(16) u16 B_s[128 * 32]; // [n][k],   8 KiB bf16 (from WT)
    __shared__ int tok_s[128];
    __shared__ float w_s[128];
    __shared__ float bias_s[128];

    const int t = threadIdx.x;
    if (t < 128) {
        int r = m0 + t;
        int rr = r < cnt ? r : cnt - 1;
        tok_s[t] = list_tok[grp * NTOK + rr] & (NTOK - 1);  // defensive clamp
        w_s[t] = (r < cnt) ? list_w[grp * NTOK + rr] : 0.f;
        bias_s[t] = bexp[e * DDIM + n0 + t];
    }
    __syncthreads();

    const int ra = t >> 2;          // staging row 0..63
    const int co = (t & 3) * 8;     // element offset within 32-elem k-chunk
    const float* xg0 = x + (size_t)tok_s[ra] * DDIM + co;
    const float* xg1 = x + (size_t)tok_s[64 + ra] * DDIM + co;
    const u16* wg0 = WT + ((size_t)e * DDIM + n0 + ra) * DDIM + co;
    const u16* wg1 = WT + ((size_t)e * DDIM + n0 + 64 + ra) * DDIM + co;
    u16* sA0 = A_s + ra * 32 + co;          // = A_s + t*8: conflict-free b128 writes
    u16* sA1 = A_s + (64 + ra) * 32 + co;
    u16* sB0 = B_s + ra * 32 + co;
    u16* sB1 = B_s + (64 + ra) * 32 + co;

    const int lane = t & 63, wave = t >> 6;
    const int wm = wave >> 1, wn = wave & 1;
    const int lm = lane & 15;
    const int ko = (lane >> 4) * 8;

    floatx4 acc[4][4];
#pragma unroll
    for (int mi = 0; mi < 4; ++mi)
#pragma unroll
        for (int ni = 0; ni < 4; ++ni) acc[mi][ni] = (floatx4){0.f, 0.f, 0.f, 0.f};

    for (int kk = 0; kk < DDIM; kk += 32) {
        float4 fa0 = *(const float4*)(xg0 + kk);
        float4 fa0b = *(const float4*)(xg0 + kk + 4);
        float4 fa1 = *(const float4*)(xg1 + kk);
        float4 fa1b = *(const float4*)(xg1 + kk + 4);
        u16x8 b0 = *(const u16x8*)(wg0 + kk);
        u16x8 b1 = *(const u16x8*)(wg1 + kk);
        u16x8 a0, a1;
        a0[0] = f2bf(fa0.x); a0[1] = f2bf(fa0.y); a0[2] = f2bf(fa0.z); a0[3] = f2bf(fa0.w);
        a0[4] = f2bf(fa0b.x); a0[5] = f2bf(fa0b.y); a0[6] = f2bf(fa0b.z); a0[7] = f2bf(fa0b.w);
        a1[0] = f2bf(fa1.x); a1[1] = f2bf(fa1.y); a1[2] = f2bf(fa1.z); a1[3] = f2bf(fa1.w);
        a1[4] = f2bf(fa1b.x); a1[5] = f2bf(fa1b.y); a1[6] = f2bf(fa1b.z); a1[7] = f2bf(fa1b.w);
        __syncthreads();            // prior iter's ds_reads done before overwrite
        *(u16x8*)sA0 = a0;
        *(u16x8*)sA1 = a1;
        *(u16x8*)sB0 = b0;
        *(u16x8*)sB1 = b1;
        __syncthreads();            // LDS writes visible
        bf16x8 af[4], bfr[4];
#pragma unroll
        for (int mi = 0; mi < 4; ++mi)
            af[mi] = *(const bf16x8*)&A_s[(wm * 64 + mi * 16 + lm) * 32 + ko];
#pragma unroll
        for (int ni = 0; ni < 4; ++ni)
            bfr[ni] = *(const bf16x8*)&B_s[(wn * 64 + ni * 16 + lm) * 32 + ko];
#pragma unroll
        for (int mi = 0; mi < 4; ++mi)
#pragma unroll
            for (int ni = 0; ni < 4; ++ni)
                acc[mi][ni] = __builtin_amdgcn_mfma_f32_16x16x32_bf16(
                    af[mi], bfr[ni], acc[mi][ni], 0, 0, 0);
    }

    // epilogue: C row = (lane>>4)*4+reg, col = lane&15 within each 16x16 tile
#pragma unroll
    for (int mi = 0; mi < 4; ++mi) {
        int rb = wm * 64 + mi * 16 + (lane >> 4) * 4;
#pragma unroll
        for (int reg = 0; reg < 4; ++reg) {
            int r = rb + reg;
            if (m0 + r < cnt) {
                size_t tok = (size_t)tok_s[r];
                float w = w_s[r];
                float* yrow = out + tok * DDIM + n0;
#pragma unroll
                for (int ni = 0; ni < 4; ++ni) {
                    int col = wn * 64 + ni * 16 + lm;
                    float v = w * (acc[mi][ni][reg] + bias_s[col]);
                    if (accum) v += yrow[col];
                    yrow[col] = v;
                }
            }
        }
    }
}

extern "C" void kernel_launch(void* const* d_in, const int* in_sizes, int n_in,
                              void* d_out, int out_size, void* d_ws, size_t ws_size,
                              hipStream_t stream) {
    const float* x     = (const float*)d_in[0];
    const float* noise = (const float*)d_in[1];
    const float* Wr    = (const float*)d_in[2];
    const float* br    = (const float*)d_in[3];
    const float* gamma = (const float*)d_in[4];
    const float* beta  = (const float*)d_in[5];
    const float* Wexp  = (const float*)d_in[6];
    const float* bexp  = (const float*)d_in[7];
    float* out = (float*)d_out;

    unsigned char* ws = (unsigned char*)d_ws;
    u16* WT       = (u16*)ws;                              // 16 MiB: WT[E][F][D] bf16
    int* counts   = (int*)(ws + 16777216);                 // 64 B (16 ints)
    int* list_tok = (int*)(ws + 16777216 + 256);           // 512 KiB: [16][NTOK]
    float* list_w = (float*)(ws + 16777216 + 256 + 524288);// 512 KiB
    // total ws use: ~17.8 MiB (known in-bounds)

    zero_counts<<<1, 64, 0, stream>>>(counts);
    transpose_w<<<dim3(16, 16, 8), 256, 0, stream>>>(Wexp, WT);
    routing_kernel<<<NTOK / 32, 256, 0, stream>>>(x, noise, Wr, br, gamma, beta,
                                                  counts, list_tok, list_w);
    moe_gemm<<<dim3(8, 64, 8), 256, 0, stream>>>(x, WT, bexp, counts, list_tok, list_w,
                                                 out, 0, 0);  // slot0: write
    moe_gemm<<<dim3(8, 64, 8), 256, 0, stream>>>(x, WT, bexp, counts, list_tok, list_w,
                                                 out, 8, 1);  // slot1: accumulate
}

// Round 5
// 259.835 us; speedup vs baseline: 1.6136x; 1.6035x over previous
//
#include <hip/hip_runtime.h>
#include <hip/hip_bf16.h>

// MoEProcessor: B=4,S=2048 -> T=8192 tokens, D=1024, E=8, K=2. fp32 in/out.
// Round 5: routing split into atomic-free routing_compute (dense per-token top2)
// + build_lists (16 blocks, ballot prefix-sum compaction). Theory: r3/r4's 195us
// routing was serialized on 16K device atomics to one cache line.
// GEMM path unchanged (known correct).

typedef unsigned short u16;
typedef __bf16 bf16x8 __attribute__((ext_vector_type(8)));
typedef float floatx4 __attribute__((ext_vector_type(4)));
typedef unsigned short u16x8 __attribute__((ext_vector_type(8)));

#define NTOK 8192
#define DDIM 1024
#define NEXP 8

__device__ __forceinline__ u16 f2bf(float f) {
    union { float f; unsigned int i; } c; c.f = f;
    unsigned int i = c.i;
    return (u16)((i + 0x7fffu + ((i >> 16) & 1u)) >> 16);
}

// -------- W_exp transpose+cast: WT[e][f][d] = bf16(W[e][d][f]) (fp32 in) --------
__global__ __launch_bounds__(256) void transpose_w(const float* __restrict__ W,
                                                   u16* __restrict__ WT) {
    __shared__ __align__(16) u16 tile[64][72];
    const int e = blockIdx.z, d0 = blockIdx.y * 64, f0 = blockIdx.x * 64;
    const int t = threadIdx.x;
    const float* src = W + (size_t)e * DDIM * DDIM;
    u16* dst = WT + (size_t)e * DDIM * DDIM;
#pragma unroll
    for (int it = 0; it < 2; ++it) {
        int idx = it * 256 + t;
        int r = idx >> 3, c8 = idx & 7;
        const float* sp = src + (size_t)(d0 + r) * DDIM + f0 + c8 * 8;
        float4 va = *(const float4*)sp;
        float4 vb = *(const float4*)(sp + 4);
        u16x8 v;
        v[0] = f2bf(va.x); v[1] = f2bf(va.y); v[2] = f2bf(va.z); v[3] = f2bf(va.w);
        v[4] = f2bf(vb.x); v[5] = f2bf(vb.y); v[6] = f2bf(vb.z); v[7] = f2bf(vb.w);
        *(u16x8*)&tile[r][c8 * 8] = v;
    }
    __syncthreads();
#pragma unroll
    for (int it = 0; it < 2; ++it) {
        int idx = it * 256 + t;
        int fr = idx >> 3, d8 = idx & 7;
        u16x8 o;
#pragma unroll
        for (int j = 0; j < 8; ++j) o[j] = tile[d8 * 8 + j][fr];
        *(u16x8*)(dst + (size_t)(f0 + fr) * DDIM + d0 + d8 * 8) = o;
    }
}

// ---- routing_compute: logits -> LN -> softmax -> +noise -> top2, NO atomics ----
__global__ __launch_bounds__(256) void routing_compute(
    const float* __restrict__ x, const float* __restrict__ noise,
    const float* __restrict__ Wr, const float* __restrict__ br,
    const float* __restrict__ gamma, const float* __restrict__ beta,
    int* __restrict__ e01, float2* __restrict__ w01) {
    __shared__ __align__(16) float wrT[NEXP][DDIM]; // 32 KiB, transposed
    const int t = threadIdx.x;
#pragma unroll
    for (int i = 0; i < 8; ++i) {
        int f4 = i * 256 + t;
        int d = f4 >> 1, half = (f4 & 1) * 4;
        float4 v = *(const float4*)&Wr[d * 8 + half];
        wrT[half + 0][d] = v.x; wrT[half + 1][d] = v.y;
        wrT[half + 2][d] = v.z; wrT[half + 3][d] = v.w;
    }
    __syncthreads();

    const int wave = t >> 6, lane = t & 63;
    const int tok = blockIdx.x * 4 + wave;
    const float4* xrow = (const float4*)(x + (size_t)tok * DDIM);
    float acc[8];
#pragma unroll
    for (int e = 0; e < 8; ++e) acc[e] = 0.f;
#pragma unroll
    for (int i = 0; i < 4; ++i) {
        int d4 = i * 64 + lane;
        float4 xv = xrow[d4];
#pragma unroll
        for (int e = 0; e < 8; ++e) {
            float4 wv = *(const float4*)&wrT[e][d4 * 4];
            acc[e] += xv.x * wv.x + xv.y * wv.y + xv.z * wv.z + xv.w * wv.w;
        }
    }
#pragma unroll
    for (int off = 32; off >= 1; off >>= 1) {
#pragma unroll
        for (int e = 0; e < 8; ++e) acc[e] += __shfl_xor(acc[e], off, 64);
    }
    if (lane == 0) {
        float lg[8], mu = 0.f;
#pragma unroll
        for (int e = 0; e < 8; ++e) { lg[e] = acc[e] + br[e]; mu += lg[e]; }
        mu *= 0.125f;
        float var = 0.f;
#pragma unroll
        for (int e = 0; e < 8; ++e) { float d = lg[e] - mu; var += d * d; }
        var *= 0.125f;
        float rstd = rsqrtf(var + 1e-5f);
        float ln[8], mx = -1e30f;
#pragma unroll
        for (int e = 0; e < 8; ++e) {
            ln[e] = (lg[e] - mu) * rstd * gamma[e] + beta[e];
            mx = fmaxf(mx, ln[e]);
        }
        float s = 0.f, p[8];
#pragma unroll
        for (int e = 0; e < 8; ++e) { p[e] = expf(ln[e] - mx); s += p[e]; }
        float inv = 1.f / s, r[8];
#pragma unroll
        for (int e = 0; e < 8; ++e) r[e] = p[e] * inv + noise[(size_t)tok * 8 + e];
        // top-2, ties -> lower index (matches jax.lax.top_k)
        int i0 = 0; float v0 = r[0];
#pragma unroll
        for (int e = 1; e < 8; ++e) if (r[e] > v0) { v0 = r[e]; i0 = e; }
        int i1 = -1; float v1 = -1e30f;
#pragma unroll
        for (int e = 0; e < 8; ++e) if (e != i0 && r[e] > v1) { v1 = r[e]; i1 = e; }
        float w0 = 1.f / (1.f + expf(v1 - v0));
        e01[tok] = i0 | (i1 << 8);
        w01[tok] = make_float2(w0, 1.f - w0);
    }
}

// ---- build_lists: one block per (slot,expert) group, ballot-compaction ----
__global__ __launch_bounds__(256) void build_lists(
    const int* __restrict__ e01, const float2* __restrict__ w01,
    int* __restrict__ counts, int* __restrict__ list_tok, float* __restrict__ list_w) {
    const int g = blockIdx.x;            // 0..15: slot = g>>3, expert = g&7
    const int slot = g >> 3, ex = g & 7;
    const int t = threadIdx.x, wave = t >> 6, lane = t & 63;
    __shared__ int wtot[4];
    int base = 0;
    for (int start = 0; start < NTOK; start += 256) {
        int tok = start + t;
        int packed = e01[tok];
        int e = slot ? ((packed >> 8) & 0xff) : (packed & 0xff);
        bool sel = (e == ex);
        unsigned long long m = __ballot(sel);
        int prefix = __popcll(m & ((1ULL << lane) - 1ULL));
        if (lane == 0) wtot[wave] = __popcll(m);
        __syncthreads();
        int wbase = 0;
#pragma unroll
        for (int wv = 0; wv < 4; ++wv) if (wv < wave) wbase += wtot[wv];
        int total = wtot[0] + wtot[1] + wtot[2] + wtot[3];
        if (sel) {
            float2 w2 = w01[tok];
            int pos = base + wbase + prefix;
            list_tok[g * NTOK + pos] = tok;
            list_w[g * NTOK + pos] = slot ? w2.y : w2.x;
        }
        base += total;
        __syncthreads();                 // wtot reused next iteration
    }
    if (t == 0) counts[g] = base;
}

// ------- grouped expert GEMM: out[tok] (+)= w*(bf16(x)@WT_e + b_e), fp32 out -------
__global__ __launch_bounds__(256) void moe_gemm(
    const float* __restrict__ x, const u16* __restrict__ WT,
    const float* __restrict__ bexp, const int* __restrict__ counts,
    const int* __restrict__ list_tok, const float* __restrict__ list_w,
    float* __restrict__ out, int grp_base, int accum) {
    const int e = blockIdx.z;
    const int grp = grp_base + e;
    int cnt = counts[grp];
    cnt = cnt < 0 ? 0 : (cnt > NTOK ? NTOK : cnt);   // defensive
    const int m0 = blockIdx.y * 128;
    if (m0 >= cnt) return;
    const int n0 = blockIdx.x * 128;

    __shared__ __align__(16) u16 A_s[128 * 32]; // [row][k], 8 KiB bf16
    __shared__ __align__(16) u16 B_s[128 * 32]; // [n][k],   8 KiB bf16 (from WT)
    __shared__ int tok_s[128];
    __shared__ float w_s[128];
    __shared__ float bias_s[128];

    const int t = threadIdx.x;
    if (t < 128) {
        int r = m0 + t;
        int rr = r < cnt ? r : cnt - 1;
        tok_s[t] = list_tok[grp * NTOK + rr] & (NTOK - 1);  // defensive clamp
        w_s[t] = (r < cnt) ? list_w[grp * NTOK + rr] : 0.f;
        bias_s[t] = bexp[e * DDIM + n0 + t];
    }
    __syncthreads();

    const int ra = t >> 2;          // staging row 0..63
    const int co = (t & 3) * 8;     // element offset within 32-elem k-chunk
    const float* xg0 = x + (size_t)tok_s[ra] * DDIM + co;
    const float* xg1 = x + (size_t)tok_s[64 + ra] * DDIM + co;
    const u16* wg0 = WT + ((size_t)e * DDIM + n0 + ra) * DDIM + co;
    const u16* wg1 = WT + ((size_t)e * DDIM + n0 + 64 + ra) * DDIM + co;
    u16* sA0 = A_s + ra * 32 + co;          // = A_s + t*8: conflict-free b128 writes
    u16* sA1 = A_s + (64 + ra) * 32 + co;
    u16* sB0 = B_s + ra * 32 + co;
    u16* sB1 = B_s + (64 + ra) * 32 + co;

    const int lane = t & 63, wave = t >> 6;
    const int wm = wave >> 1, wn = wave & 1;
    const int lm = lane & 15;
    const int ko = (lane >> 4) * 8;

    floatx4 acc[4][4];
#pragma unroll
    for (int mi = 0; mi < 4; ++mi)
#pragma unroll
        for (int ni = 0; ni < 4; ++ni) acc[mi][ni] = (floatx4){0.f, 0.f, 0.f, 0.f};

    for (int kk = 0; kk < DDIM; kk += 32) {
        float4 fa0 = *(const float4*)(xg0 + kk);
        float4 fa0b = *(const float4*)(xg0 + kk + 4);
        float4 fa1 = *(const float4*)(xg1 + kk);
        float4 fa1b = *(const float4*)(xg1 + kk + 4);
        u16x8 b0 = *(const u16x8*)(wg0 + kk);
        u16x8 b1 = *(const u16x8*)(wg1 + kk);
        u16x8 a0, a1;
        a0[0] = f2bf(fa0.x); a0[1] = f2bf(fa0.y); a0[2] = f2bf(fa0.z); a0[3] = f2bf(fa0.w);
        a0[4] = f2bf(fa0b.x); a0[5] = f2bf(fa0b.y); a0[6] = f2bf(fa0b.z); a0[7] = f2bf(fa0b.w);
        a1[0] = f2bf(fa1.x); a1[1] = f2bf(fa1.y); a1[2] = f2bf(fa1.z); a1[3] = f2bf(fa1.w);
        a1[4] = f2bf(fa1b.x); a1[5] = f2bf(fa1b.y); a1[6] = f2bf(fa1b.z); a1[7] = f2bf(fa1b.w);
        __syncthreads();            // prior iter's ds_reads done before overwrite
        *(u16x8*)sA0 = a0;
        *(u16x8*)sA1 = a1;
        *(u16x8*)sB0 = b0;
        *(u16x8*)sB1 = b1;
        __syncthreads();            // LDS writes visible
        bf16x8 af[4], bfr[4];
#pragma unroll
        for (int mi = 0; mi < 4; ++mi)
            af[mi] = *(const bf16x8*)&A_s[(wm * 64 + mi * 16 + lm) * 32 + ko];
#pragma unroll
        for (int ni = 0; ni < 4; ++ni)
            bfr[ni] = *(const bf16x8*)&B_s[(wn * 64 + ni * 16 + lm) * 32 + ko];
#pragma unroll
        for (int mi = 0; mi < 4; ++mi)
#pragma unroll
            for (int ni = 0; ni < 4; ++ni)
                acc[mi][ni] = __builtin_amdgcn_mfma_f32_16x16x32_bf16(
                    af[mi], bfr[ni], acc[mi][ni], 0, 0, 0);
    }

    // epilogue: C row = (lane>>4)*4+reg, col = lane&15 within each 16x16 tile
#pragma unroll
    for (int mi = 0; mi < 4; ++mi) {
        int rb = wm * 64 + mi * 16 + (lane >> 4) * 4;
#pragma unroll
        for (int reg = 0; reg < 4; ++reg) {
            int r = rb + reg;
            if (m0 + r < cnt) {
                size_t tok = (size_t)tok_s[r];
                float w = w_s[r];
                float* yrow = out + tok * DDIM + n0;
#pragma unroll
                for (int ni = 0; ni < 4; ++ni) {
                    int col = wn * 64 + ni * 16 + lm;
                    float v = w * (acc[mi][ni][reg] + bias_s[col]);
                    if (accum) v += yrow[col];
                    yrow[col] = v;
                }
            }
        }
    }
}

extern "C" void kernel_launch(void* const* d_in, const int* in_sizes, int n_in,
                              void* d_out, int out_size, void* d_ws, size_t ws_size,
                              hipStream_t stream) {
    const float* x     = (const float*)d_in[0];
    const float* noise = (const float*)d_in[1];
    const float* Wr    = (const float*)d_in[2];
    const float* br    = (const float*)d_in[3];
    const float* gamma = (const float*)d_in[4];
    const float* beta  = (const float*)d_in[5];
    const float* Wexp  = (const float*)d_in[6];
    const float* bexp  = (const float*)d_in[7];
    float* out = (float*)d_out;

    unsigned char* ws = (unsigned char*)d_ws;
    u16* WT       = (u16*)ws;                               // 16 MiB: WT[E][F][D] bf16
    int* counts   = (int*)(ws + 16777216);                  // 64 B (16 ints)
    int* list_tok = (int*)(ws + 16777216 + 256);            // 512 KiB: [16][NTOK]
    float* list_w = (float*)(ws + 16777216 + 256 + 524288); // 512 KiB
    int* e01      = (int*)(ws + 16777216 + 256 + 1048576);  // 32 KiB
    float2* w01   = (float2*)(ws + 16777216 + 256 + 1048576 + 32768); // 64 KiB
    // total ws use: ~17.9 MiB

    transpose_w<<<dim3(16, 16, 8), 256, 0, stream>>>(Wexp, WT);
    routing_compute<<<NTOK / 4, 256, 0, stream>>>(x, noise, Wr, br, gamma, beta,
                                                  e01, w01);
    build_lists<<<16, 256, 0, stream>>>(e01, w01, counts, list_tok, list_w);
    moe_gemm<<<dim3(8, 64, 8), 256, 0, stream>>>(x, WT, bexp, counts, list_tok, list_w,
                                                 out, 0, 0);  // slot0: write
    moe_gemm<<<dim3(8, 64, 8), 256, 0, stream>>>(x, WT, bexp, counts, list_tok, list_w,
                                                 out, 8, 1);  // slot1: accumulate
}

// Round 6
// 253.397 us; speedup vs baseline: 1.6546x; 1.0254x over previous
//
#include <hip/hip_runtime.h>
#include <hip/hip_bf16.h>

// MoEProcessor: B=4,S=2048 -> T=8192 tokens, D=1024, E=8, K=2. fp32 in/out.
// Round 6: (a) pre-cast x to bf16 (ws-size gated), (b) XCD-aware grid remap so the
// 8 n-tiles of one m-tile share an XCD L2 (A re-fetch was 156MB/pass), (c) XOR
// bank swizzle on LDS frag layout (2.2M conflicts -> ~0).

typedef unsigned short u16;
typedef __bf16 bf16x8 __attribute__((ext_vector_type(8)));
typedef float floatx4 __attribute__((ext_vector_type(4)));
typedef unsigned short u16x8 __attribute__((ext_vector_type(8)));

#define NTOK 8192
#define DDIM 1024
#define NEXP 8

__device__ __forceinline__ u16 f2bf(float f) {
    union { float f; unsigned int i; } c; c.f = f;
    unsigned int i = c.i;
    return (u16)((i + 0x7fffu + ((i >> 16) & 1u)) >> 16);
}

// LDS address swizzle: row stride 32 u16; chunk (8 u16 = 16B) XOR'd by row bits
// so 16-consecutive-row b128 reads spread across all 32 banks (2 lanes/bank).
__device__ __forceinline__ int swz(int row, int chunk) {
    return row * 32 + ((chunk ^ ((row >> 1) & 3)) << 3);
}

// -------- xcast: xb[tok][d] = bf16(x[tok][d]) --------
__global__ __launch_bounds__(256) void xcast(const float* __restrict__ x,
                                             u16* __restrict__ xb) {
    size_t i = ((size_t)blockIdx.x * 256 + threadIdx.x) * 8;
    float4 a = *(const float4*)(x + i);
    float4 b = *(const float4*)(x + i + 4);
    u16x8 v;
    v[0] = f2bf(a.x); v[1] = f2bf(a.y); v[2] = f2bf(a.z); v[3] = f2bf(a.w);
    v[4] = f2bf(b.x); v[5] = f2bf(b.y); v[6] = f2bf(b.z); v[7] = f2bf(b.w);
    *(u16x8*)(xb + i) = v;
}

// -------- W_exp transpose+cast: WT[e][f][d] = bf16(W[e][d][f]) (fp32 in) --------
__global__ __launch_bounds__(256) void transpose_w(const float* __restrict__ W,
                                                   u16* __restrict__ WT) {
    __shared__ __align__(16) u16 tile[64][72];
    const int e = blockIdx.z, d0 = blockIdx.y * 64, f0 = blockIdx.x * 64;
    const int t = threadIdx.x;
    const float* src = W + (size_t)e * DDIM * DDIM;
    u16* dst = WT + (size_t)e * DDIM * DDIM;
#pragma unroll
    for (int it = 0; it < 2; ++it) {
        int idx = it * 256 + t;
        int r = idx >> 3, c8 = idx & 7;
        const float* sp = src + (size_t)(d0 + r) * DDIM + f0 + c8 * 8;
        float4 va = *(const float4*)sp;
        float4 vb = *(const float4*)(sp + 4);
        u16x8 v;
        v[0] = f2bf(va.x); v[1] = f2bf(va.y); v[2] = f2bf(va.z); v[3] = f2bf(va.w);
        v[4] = f2bf(vb.x); v[5] = f2bf(vb.y); v[6] = f2bf(vb.z); v[7] = f2bf(vb.w);
        *(u16x8*)&tile[r][c8 * 8] = v;
    }
    __syncthreads();
#pragma unroll
    for (int it = 0; it < 2; ++it) {
        int idx = it * 256 + t;
        int fr = idx >> 3, d8 = idx & 7;
        u16x8 o;
#pragma unroll
        for (int j = 0; j < 8; ++j) o[j] = tile[d8 * 8 + j][fr];
        *(u16x8*)(dst + (size_t)(f0 + fr) * DDIM + d0 + d8 * 8) = o;
    }
}

// ---- routing_compute: logits -> LN -> softmax -> +noise -> top2, NO atomics ----
__global__ __launch_bounds__(256) void routing_compute(
    const float* __restrict__ x, const float* __restrict__ noise,
    const float* __restrict__ Wr, const float* __restrict__ br,
    const float* __restrict__ gamma, const float* __restrict__ beta,
    int* __restrict__ e01, float2* __restrict__ w01) {
    __shared__ __align__(16) float wrT[NEXP][DDIM]; // 32 KiB, transposed
    const int t = threadIdx.x;
#pragma unroll
    for (int i = 0; i < 8; ++i) {
        int f4 = i * 256 + t;
        int d = f4 >> 1, half = (f4 & 1) * 4;
        float4 v = *(const float4*)&Wr[d * 8 + half];
        wrT[half + 0][d] = v.x; wrT[half + 1][d] = v.y;
        wrT[half + 2][d] = v.z; wrT[half + 3][d] = v.w;
    }
    __syncthreads();

    const int wave = t >> 6, lane = t & 63;
    const int tok = blockIdx.x * 4 + wave;
    const float4* xrow = (const float4*)(x + (size_t)tok * DDIM);
    float acc[8];
#pragma unroll
    for (int e = 0; e < 8; ++e) acc[e] = 0.f;
#pragma unroll
    for (int i = 0; i < 4; ++i) {
        int d4 = i * 64 + lane;
        float4 xv = xrow[d4];
#pragma unroll
        for (int e = 0; e < 8; ++e) {
            float4 wv = *(const float4*)&wrT[e][d4 * 4];
            acc[e] += xv.x * wv.x + xv.y * wv.y + xv.z * wv.z + xv.w * wv.w;
        }
    }
#pragma unroll
    for (int off = 32; off >= 1; off >>= 1) {
#pragma unroll
        for (int e = 0; e < 8; ++e) acc[e] += __shfl_xor(acc[e], off, 64);
    }
    if (lane == 0) {
        float lg[8], mu = 0.f;
#pragma unroll
        for (int e = 0; e < 8; ++e) { lg[e] = acc[e] + br[e]; mu += lg[e]; }
        mu *= 0.125f;
        float var = 0.f;
#pragma unroll
        for (int e = 0; e < 8; ++e) { float d = lg[e] - mu; var += d * d; }
        var *= 0.125f;
        float rstd = rsqrtf(var + 1e-5f);
        float ln[8], mx = -1e30f;
#pragma unroll
        for (int e = 0; e < 8; ++e) {
            ln[e] = (lg[e] - mu) * rstd * gamma[e] + beta[e];
            mx = fmaxf(mx, ln[e]);
        }
        float s = 0.f, p[8];
#pragma unroll
        for (int e = 0; e < 8; ++e) { p[e] = expf(ln[e] - mx); s += p[e]; }
        float inv = 1.f / s, r[8];
#pragma unroll
        for (int e = 0; e < 8; ++e) r[e] = p[e] * inv + noise[(size_t)tok * 8 + e];
        int i0 = 0; float v0 = r[0];
#pragma unroll
        for (int e = 1; e < 8; ++e) if (r[e] > v0) { v0 = r[e]; i0 = e; }
        int i1 = -1; float v1 = -1e30f;
#pragma unroll
        for (int e = 0; e < 8; ++e) if (e != i0 && r[e] > v1) { v1 = r[e]; i1 = e; }
        float w0 = 1.f / (1.f + expf(v1 - v0));
        e01[tok] = i0 | (i1 << 8);
        w01[tok] = make_float2(w0, 1.f - w0);
    }
}

// ---- build_lists: one block per (slot,expert) group, ballot-compaction ----
__global__ __launch_bounds__(256) void build_lists(
    const int* __restrict__ e01, const float2* __restrict__ w01,
    int* __restrict__ counts, int* __restrict__ list_tok, float* __restrict__ list_w) {
    const int g = blockIdx.x;            // 0..15: slot = g>>3, expert = g&7
    const int slot = g >> 3, ex = g & 7;
    const int t = threadIdx.x, wave = t >> 6, lane = t & 63;
    __shared__ int wtot[4];
    int base = 0;
    for (int start = 0; start < NTOK; start += 256) {
        int tok = start + t;
        int packed = e01[tok];
        int e = slot ? ((packed >> 8) & 0xff) : (packed & 0xff);
        bool sel = (e == ex);
        unsigned long long m = __ballot(sel);
        int prefix = __popcll(m & ((1ULL << lane) - 1ULL));
        if (lane == 0) wtot[wave] = __popcll(m);
        __syncthreads();
        int wbase = 0;
#pragma unroll
        for (int wv = 0; wv < 4; ++wv) if (wv < wave) wbase += wtot[wv];
        int total = wtot[0] + wtot[1] + wtot[2] + wtot[3];
        if (sel) {
            float2 w2 = w01[tok];
            int pos = base + wbase + prefix;
            list_tok[g * NTOK + pos] = tok;
            list_w[g * NTOK + pos] = slot ? w2.y : w2.x;
        }
        base += total;
        __syncthreads();
    }
    if (t == 0) counts[g] = base;
}

// ------- grouped expert GEMM: out[tok] (+)= w*(bf16(x)@WT_e + b_e), fp32 out -------
// Grid: (512,1,8). lin=blockIdx.x decode puts the 8 n-tiles of one m-tile at linear
// ids differing by 8 -> same XCD under round-robin -> A rows shared in that XCD's L2.
template <int BF16A>
__global__ __launch_bounds__(256) void moe_gemm(
    const float* __restrict__ xf, const u16* __restrict__ xb,
    const u16* __restrict__ WT, const float* __restrict__ bexp,
    const int* __restrict__ counts, const int* __restrict__ list_tok,
    const float* __restrict__ list_w, float* __restrict__ out,
    int grp_base, int accum) {
    const int e = blockIdx.z;
    const int grp = grp_base + e;
    int cnt = counts[grp];
    cnt = cnt < 0 ? 0 : (cnt > NTOK ? NTOK : cnt);
    const int lin = blockIdx.x;
    const int n = (lin >> 3) & 7;
    const int m = (lin & 7) | ((lin >> 6) << 3);
    const int m0 = m * 128;
    if (m0 >= cnt) return;
    const int n0 = n * 128;

    __shared__ __align__(16) u16 A_s[128 * 32]; // [row][k] bf16, XOR-swizzled chunks
    __shared__ __align__(16) u16 B_s[128 * 32];
    __shared__ int tok_s[128];
    __shared__ float w_s[128];
    __shared__ float bias_s[128];

    const int t = threadIdx.x;
    if (t < 128) {
        int r = m0 + t;
        int rr = r < cnt ? r : cnt - 1;
        tok_s[t] = list_tok[grp * NTOK + rr] & (NTOK - 1);
        w_s[t] = (r < cnt) ? list_w[grp * NTOK + rr] : 0.f;
        bias_s[t] = bexp[e * DDIM + n0 + t];
    }
    __syncthreads();

    const int ra = t >> 2;          // staging row 0..63
    const int ch = t & 3;           // k-chunk 0..3 (8 elems each)
    const int co = ch * 8;
    const u16* wg0 = WT + ((size_t)e * DDIM + n0 + ra) * DDIM + co;
    const u16* wg1 = WT + ((size_t)e * DDIM + n0 + 64 + ra) * DDIM + co;
    u16* sA0 = A_s + swz(ra, ch);
    u16* sA1 = A_s + swz(64 + ra, ch);
    u16* sB0 = B_s + swz(ra, ch);
    u16* sB1 = B_s + swz(64 + ra, ch);

    const int lane = t & 63, wave = t >> 6;
    const int wm = wave >> 1, wn = wave & 1;
    const int lm = lane & 15;
    const int kc = lane >> 4;       // frag k-chunk 0..3

    floatx4 acc[4][4];
#pragma unroll
    for (int mi = 0; mi < 4; ++mi)
#pragma unroll
        for (int ni = 0; ni < 4; ++ni) acc[mi][ni] = (floatx4){0.f, 0.f, 0.f, 0.f};

    const float* xg0f = xf + (size_t)tok_s[ra] * DDIM + co;
    const float* xg1f = xf + (size_t)tok_s[64 + ra] * DDIM + co;
    const u16* xg0b = xb + (size_t)tok_s[ra] * DDIM + co;
    const u16* xg1b = xb + (size_t)tok_s[64 + ra] * DDIM + co;

    for (int kk = 0; kk < DDIM; kk += 32) {
        u16x8 a0, a1;
        if (BF16A) {
            a0 = *(const u16x8*)(xg0b + kk);
            a1 = *(const u16x8*)(xg1b + kk);
        } else {
            float4 fa0 = *(const float4*)(xg0f + kk);
            float4 fa0b = *(const float4*)(xg0f + kk + 4);
            float4 fa1 = *(const float4*)(xg1f + kk);
            float4 fa1b = *(const float4*)(xg1f + kk + 4);
            a0[0] = f2bf(fa0.x); a0[1] = f2bf(fa0.y); a0[2] = f2bf(fa0.z); a0[3] = f2bf(fa0.w);
            a0[4] = f2bf(fa0b.x); a0[5] = f2bf(fa0b.y); a0[6] = f2bf(fa0b.z); a0[7] = f2bf(fa0b.w);
            a1[0] = f2bf(fa1.x); a1[1] = f2bf(fa1.y); a1[2] = f2bf(fa1.z); a1[3] = f2bf(fa1.w);
            a1[4] = f2bf(fa1b.x); a1[5] = f2bf(fa1b.y); a1[6] = f2bf(fa1b.z); a1[7] = f2bf(fa1b.w);
        }
        u16x8 b0 = *(const u16x8*)(wg0 + kk);
        u16x8 b1 = *(const u16x8*)(wg1 + kk);
        __syncthreads();
        *(u16x8*)sA0 = a0;
        *(u16x8*)sA1 = a1;
        *(u16x8*)sB0 = b0;
        *(u16x8*)sB1 = b1;
        __syncthreads();
        bf16x8 af[4], bfr[4];
#pragma unroll
        for (int mi = 0; mi < 4; ++mi)
            af[mi] = *(const bf16x8*)&A_s[swz(wm * 64 + mi * 16 + lm, kc)];
#pragma unroll
        for (int ni = 0; ni < 4; ++ni)
            bfr[ni] = *(const bf16x8*)&B_s[swz(wn * 64 + ni * 16 + lm, kc)];
#pragma unroll
        for (int mi = 0; mi < 4; ++mi)
#pragma unroll
            for (int ni = 0; ni < 4; ++ni)
                acc[mi][ni] = __builtin_amdgcn_mfma_f32_16x16x32_bf16(
                    af[mi], bfr[ni], acc[mi][ni], 0, 0, 0);
    }

#pragma unroll
    for (int mi = 0; mi < 4; ++mi) {
        int rb = wm * 64 + mi * 16 + (lane >> 4) * 4;
#pragma unroll
        for (int reg = 0; reg < 4; ++reg) {
            int r = rb + reg;
            if (m0 + r < cnt) {
                size_t tok = (size_t)tok_s[r];
                float w = w_s[r];
                float* yrow = out + tok * DDIM + n0;
#pragma unroll
                for (int ni = 0; ni < 4; ++ni) {
                    int col = wn * 64 + ni * 16 + lm;
                    float v = w * (acc[mi][ni][reg] + bias_s[col]);
                    if (accum) v += yrow[col];
                    yrow[col] = v;
                }
            }
        }
    }
}

extern "C" void kernel_launch(void* const* d_in, const int* in_sizes, int n_in,
                              void* d_out, int out_size, void* d_ws, size_t ws_size,
                              hipStream_t stream) {
    const float* x     = (const float*)d_in[0];
    const float* noise = (const float*)d_in[1];
    const float* Wr    = (const float*)d_in[2];
    const float* br    = (const float*)d_in[3];
    const float* gamma = (const float*)d_in[4];
    const float* beta  = (const float*)d_in[5];
    const float* Wexp  = (const float*)d_in[6];
    const float* bexp  = (const float*)d_in[7];
    float* out = (float*)d_out;

    unsigned char* ws = (unsigned char*)d_ws;
    u16* WT       = (u16*)ws;                               // 16 MiB
    int* counts   = (int*)(ws + 16777216);                  // 64 B
    int* list_tok = (int*)(ws + 16777472);                  // 512 KiB
    float* list_w = (float*)(ws + 17301760);                // 512 KiB
    int* e01      = (int*)(ws + 17826048);                  // 32 KiB
    float2* w01   = (float2*)(ws + 17858816);               // 64 KiB
    u16* xb       = (u16*)(ws + 17924352);                  // 16 MiB (optional)
    const size_t need_bf16a = 17924352 + 16777216;          // ~33.1 MiB

    transpose_w<<<dim3(16, 16, 8), 256, 0, stream>>>(Wexp, WT);
    routing_compute<<<NTOK / 4, 256, 0, stream>>>(x, noise, Wr, br, gamma, beta,
                                                  e01, w01);
    build_lists<<<16, 256, 0, stream>>>(e01, w01, counts, list_tok, list_w);

    if (ws_size >= need_bf16a) {
        xcast<<<NTOK * DDIM / (256 * 8), 256, 0, stream>>>(x, xb);
        moe_gemm<1><<<dim3(512, 1, 8), 256, 0, stream>>>(
            x, xb, WT, bexp, counts, list_tok, list_w, out, 0, 0);
        moe_gemm<1><<<dim3(512, 1, 8), 256, 0, stream>>>(
            x, xb, WT, bexp, counts, list_tok, list_w, out, 8, 1);
    } else {
        moe_gemm<0><<<dim3(512, 1, 8), 256, 0, stream>>>(
            x, xb, WT, bexp, counts, list_tok, list_w, out, 0, 0);
        moe_gemm<0><<<dim3(512, 1, 8), 256, 0, stream>>>(
            x, xb, WT, bexp, counts, list_tok, list_w, out, 8, 1);
    }
}

// Round 7
// 238.956 us; speedup vs baseline: 1.7546x; 1.0604x over previous
//
#include <hip/hip_runtime.h>
#include <hip/hip_bf16.h>

// MoEProcessor: B=4,S=2048 -> T=8192 tokens, D=1024, E=8, K=2. fp32 in/out.
// Round 7: (1) transpose_w conflict-free rewrite (fp32 tile, stride 65),
// (2) gemm: BK=64 + register prefetch pipeline (hide global latency at 2 waves/SIMD),
// (3) expert->XCD affinity (id%8==e): A-rows and W-slice both L2-resident per XCD.

typedef unsigned short u16;
typedef __bf16 bf16x8 __attribute__((ext_vector_type(8)));
typedef float floatx4 __attribute__((ext_vector_type(4)));
typedef unsigned short u16x8 __attribute__((ext_vector_type(8)));

#define NTOK 8192
#define DDIM 1024
#define NEXP 8

__device__ __forceinline__ u16 f2bf(float f) {
    union { float f; unsigned int i; } c; c.f = f;
    unsigned int i = c.i;
    return (u16)((i + 0x7fffu + ((i >> 16) & 1u)) >> 16);
}

// -------- xcast: xb[tok][d] = bf16(x[tok][d]) --------
__global__ __launch_bounds__(256) void xcast(const float* __restrict__ x,
                                             u16* __restrict__ xb) {
    size_t i = ((size_t)blockIdx.x * 256 + threadIdx.x) * 8;
    float4 a = *(const float4*)(x + i);
    float4 b = *(const float4*)(x + i + 4);
    u16x8 v;
    v[0] = f2bf(a.x); v[1] = f2bf(a.y); v[2] = f2bf(a.z); v[3] = f2bf(a.w);
    v[4] = f2bf(b.x); v[5] = f2bf(b.y); v[6] = f2bf(b.z); v[7] = f2bf(b.w);
    *(u16x8*)(xb + i) = v;
}

// -------- W_exp transpose+cast: WT[e][f][d] = bf16(W[e][d][f]) --------
// fp32 LDS tile, stride 65 (65%32==1): phase-1 scalar writes bank=(c+16q+r)%32 and
// phase-2 scalar reads bank=(c2+16q+i)%32 are both 2 lanes/bank (free).
__global__ __launch_bounds__(256) void transpose_w(const float* __restrict__ W,
                                                   u16* __restrict__ WT) {
    __shared__ float tileT[64 * 65]; // 16.6 KiB, [f][d] logical, stride 65
    const int e = blockIdx.z, d0 = blockIdx.y * 64, f0 = blockIdx.x * 64;
    const int t = threadIdx.x;
    const float* src = W + (size_t)e * DDIM * DDIM;
    u16* dst = WT + (size_t)e * DDIM * DDIM;
    const int r = t >> 2, q = t & 3;
    const float* sp = src + (size_t)(d0 + r) * DDIM + f0 + q * 16;
#pragma unroll
    for (int j = 0; j < 4; ++j) {
        float4 v = *(const float4*)(sp + j * 4);
        int c = q * 16 + j * 4;
        tileT[(c + 0) * 65 + r] = v.x;
        tileT[(c + 1) * 65 + r] = v.y;
        tileT[(c + 2) * 65 + r] = v.z;
        tileT[(c + 3) * 65 + r] = v.w;
    }
    __syncthreads();
    const int c2 = t >> 2, dq = (t & 3) * 16;
    u16x8 o0, o1;
#pragma unroll
    for (int i = 0; i < 8; ++i) o0[i] = f2bf(tileT[c2 * 65 + dq + i]);
#pragma unroll
    for (int i = 0; i < 8; ++i) o1[i] = f2bf(tileT[c2 * 65 + dq + 8 + i]);
    u16* dp = dst + (size_t)(f0 + c2) * DDIM + d0 + dq;
    *(u16x8*)dp = o0;
    *(u16x8*)(dp + 8) = o1;
}

// ---- routing_compute: logits -> LN -> softmax -> +noise -> top2, NO atomics ----
__global__ __launch_bounds__(256) void routing_compute(
    const float* __restrict__ x, const float* __restrict__ noise,
    const float* __restrict__ Wr, const float* __restrict__ br,
    const float* __restrict__ gamma, const float* __restrict__ beta,
    int* __restrict__ e01, float2* __restrict__ w01) {
    __shared__ __align__(16) float wrT[NEXP][DDIM]; // 32 KiB, transposed
    const int t = threadIdx.x;
#pragma unroll
    for (int i = 0; i < 8; ++i) {
        int f4 = i * 256 + t;
        int d = f4 >> 1, half = (f4 & 1) * 4;
        float4 v = *(const float4*)&Wr[d * 8 + half];
        wrT[half + 0][d] = v.x; wrT[half + 1][d] = v.y;
        wrT[half + 2][d] = v.z; wrT[half + 3][d] = v.w;
    }
    __syncthreads();

    const int wave = t >> 6, lane = t & 63;
    const int tok = blockIdx.x * 4 + wave;
    const float4* xrow = (const float4*)(x + (size_t)tok * DDIM);
    float acc[8];
#pragma unroll
    for (int e = 0; e < 8; ++e) acc[e] = 0.f;
#pragma unroll
    for (int i = 0; i < 4; ++i) {
        int d4 = i * 64 + lane;
        float4 xv = xrow[d4];
#pragma unroll
        for (int e = 0; e < 8; ++e) {
            float4 wv = *(const float4*)&wrT[e][d4 * 4];
            acc[e] += xv.x * wv.x + xv.y * wv.y + xv.z * wv.z + xv.w * wv.w;
        }
    }
#pragma unroll
    for (int off = 32; off >= 1; off >>= 1) {
#pragma unroll
        for (int e = 0; e < 8; ++e) acc[e] += __shfl_xor(acc[e], off, 64);
    }
    if (lane == 0) {
        float lg[8], mu = 0.f;
#pragma unroll
        for (int e = 0; e < 8; ++e) { lg[e] = acc[e] + br[e]; mu += lg[e]; }
        mu *= 0.125f;
        float var = 0.f;
#pragma unroll
        for (int e = 0; e < 8; ++e) { float d = lg[e] - mu; var += d * d; }
        var *= 0.125f;
        float rstd = rsqrtf(var + 1e-5f);
        float ln[8], mx = -1e30f;
#pragma unroll
        for (int e = 0; e < 8; ++e) {
            ln[e] = (lg[e] - mu) * rstd * gamma[e] + beta[e];
            mx = fmaxf(mx, ln[e]);
        }
        float s = 0.f, p[8];
#pragma unroll
        for (int e = 0; e < 8; ++e) { p[e] = expf(ln[e] - mx); s += p[e]; }
        float inv = 1.f / s, r[8];
#pragma unroll
        for (int e = 0; e < 8; ++e) r[e] = p[e] * inv + noise[(size_t)tok * 8 + e];
        int i0 = 0; float v0 = r[0];
#pragma unroll
        for (int e = 1; e < 8; ++e) if (r[e] > v0) { v0 = r[e]; i0 = e; }
        int i1 = -1; float v1 = -1e30f;
#pragma unroll
        for (int e = 0; e < 8; ++e) if (e != i0 && r[e] > v1) { v1 = r[e]; i1 = e; }
        float w0 = 1.f / (1.f + expf(v1 - v0));
        e01[tok] = i0 | (i1 << 8);
        w01[tok] = make_float2(w0, 1.f - w0);
    }
}

// ---- build_lists: one block per (slot,expert) group, ballot-compaction ----
__global__ __launch_bounds__(256) void build_lists(
    const int* __restrict__ e01, const float2* __restrict__ w01,
    int* __restrict__ counts, int* __restrict__ list_tok, float* __restrict__ list_w) {
    const int g = blockIdx.x;            // 0..15: slot = g>>3, expert = g&7
    const int slot = g >> 3, ex = g & 7;
    const int t = threadIdx.x, wave = t >> 6, lane = t & 63;
    __shared__ int wtot[4];
    int base = 0;
    for (int start = 0; start < NTOK; start += 256) {
        int tok = start + t;
        int packed = e01[tok];
        int e = slot ? ((packed >> 8) & 0xff) : (packed & 0xff);
        bool sel = (e == ex);
        unsigned long long m = __ballot(sel);
        int prefix = __popcll(m & ((1ULL << lane) - 1ULL));
        if (lane == 0) wtot[wave] = __popcll(m);
        __syncthreads();
        int wbase = 0;
#pragma unroll
        for (int wv = 0; wv < 4; ++wv) if (wv < wave) wbase += wtot[wv];
        int total = wtot[0] + wtot[1] + wtot[2] + wtot[3];
        if (sel) {
            float2 w2 = w01[tok];
            int pos = base + wbase + prefix;
            list_tok[g * NTOK + pos] = tok;
            list_w[g * NTOK + pos] = slot ? w2.y : w2.x;
        }
        base += total;
        __syncthreads();
    }
    if (t == 0) counts[g] = base;
}

// ------- grouped expert GEMM: out[tok] (+)= w*(bf16(x)@WT_e + b_e), fp32 out -------
// 1D grid 4096: id%8 = expert (XCD affinity), then n = (id>>3)&7, m = id>>6.
// BK=64 K-loop with register prefetch: loads for iter k+1 issue before iter k's MFMAs.
template <int BF16A>
__global__ __launch_bounds__(256) void moe_gemm(
    const float* __restrict__ xf, const u16* __restrict__ xb,
    const u16* __restrict__ WT, const float* __restrict__ bexp,
    const int* __restrict__ counts, const int* __restrict__ list_tok,
    const float* __restrict__ list_w, float* __restrict__ out,
    int grp_base, int accum) {
    const int id = blockIdx.x;
    const int e = id & 7;
    const int n = (id >> 3) & 7;
    const int m = id >> 6;
    const int grp = grp_base + e;
    int cnt = counts[grp];
    cnt = cnt < 0 ? 0 : (cnt > NTOK ? NTOK : cnt);
    const int m0 = m * 128;
    if (m0 >= cnt) return;
    const int n0 = n * 128;

    __shared__ __align__(16) u16 A_s[128 * 64]; // 16 KiB, [row][k], chunk^=(row&7)
    __shared__ __align__(16) u16 B_s[128 * 64]; // 16 KiB
    __shared__ int tok_s[128];
    __shared__ float w_s[128];
    __shared__ float bias_s[128];

    const int t = threadIdx.x;
    if (t < 128) {
        int r = m0 + t;
        int rr = r < cnt ? r : cnt - 1;
        tok_s[t] = list_tok[grp * NTOK + rr] & (NTOK - 1);
        w_s[t] = (r < cnt) ? list_w[grp * NTOK + rr] : 0.f;
        bias_s[t] = bexp[e * DDIM + n0 + t];
    }
    __syncthreads();

    const int sr = t >> 3;          // staging row base 0..31 (rows s*32+sr)
    const int ch = t & 7;           // k-chunk 0..7 (8 u16 = 16B)
    const int co = ch * 8;

    size_t arow[4];
    u16 *adst[4], *bdst[4];
#pragma unroll
    for (int s = 0; s < 4; ++s) {
        int row = s * 32 + sr;
        arow[s] = (size_t)tok_s[row] * DDIM + co;
        int cs = ((ch ^ (row & 7)) << 3);
        adst[s] = A_s + row * 64 + cs;
        bdst[s] = B_s + row * 64 + cs;
    }
    const u16* bsrc = WT + ((size_t)e * DDIM + n0 + sr) * DDIM + co;

    const int lane = t & 63, wave = t >> 6;
    const int wm = wave >> 1, wn = wave & 1;
    const int lm = lane & 15, kc = lane >> 4;

    floatx4 acc[4][4];
#pragma unroll
    for (int mi = 0; mi < 4; ++mi)
#pragma unroll
        for (int ni = 0; ni < 4; ++ni) acc[mi][ni] = (floatx4){0.f, 0.f, 0.f, 0.f};

    u16x8 pa[4], pb[4];
    float4 pfa[4][2];
#pragma unroll
    for (int s = 0; s < 4; ++s) {
        if (BF16A) {
            pa[s] = *(const u16x8*)(xb + arow[s]);
        } else {
            pfa[s][0] = *(const float4*)(xf + arow[s]);
            pfa[s][1] = *(const float4*)(xf + arow[s] + 4);
        }
        pb[s] = *(const u16x8*)(bsrc + (size_t)s * 32 * DDIM);
    }

    for (int kk = 0; kk < DDIM; kk += 64) {
        u16x8 wa[4];
#pragma unroll
        for (int s = 0; s < 4; ++s) {
            if (BF16A) {
                wa[s] = pa[s];
            } else {
                wa[s][0] = f2bf(pfa[s][0].x); wa[s][1] = f2bf(pfa[s][0].y);
                wa[s][2] = f2bf(pfa[s][0].z); wa[s][3] = f2bf(pfa[s][0].w);
                wa[s][4] = f2bf(pfa[s][1].x); wa[s][5] = f2bf(pfa[s][1].y);
                wa[s][6] = f2bf(pfa[s][1].z); wa[s][7] = f2bf(pfa[s][1].w);
            }
        }
        __syncthreads();            // prior iter's ds_reads done before overwrite
#pragma unroll
        for (int s = 0; s < 4; ++s) {
            *(u16x8*)adst[s] = wa[s];
            *(u16x8*)bdst[s] = pb[s];
        }
        __syncthreads();
        const int nk = kk + 64;     // prefetch next iter: overlaps with MFMAs below
        if (nk < DDIM) {
#pragma unroll
            for (int s = 0; s < 4; ++s) {
                if (BF16A) {
                    pa[s] = *(const u16x8*)(xb + arow[s] + nk);
                } else {
                    pfa[s][0] = *(const float4*)(xf + arow[s] + nk);
                    pfa[s][1] = *(const float4*)(xf + arow[s] + nk + 4);
                }
                pb[s] = *(const u16x8*)(bsrc + (size_t)s * 32 * DDIM + nk);
            }
        }
#pragma unroll
        for (int ks = 0; ks < 2; ++ks) {
            bf16x8 af[4], bfr[4];
#pragma unroll
            for (int mi = 0; mi < 4; ++mi) {
                int row = wm * 64 + mi * 16 + lm;
                int c = (((ks * 4 + kc) ^ (row & 7)) << 3);
                af[mi] = *(const bf16x8*)&A_s[row * 64 + c];
            }
#pragma unroll
            for (int ni = 0; ni < 4; ++ni) {
                int row = wn * 64 + ni * 16 + lm;
                int c = (((ks * 4 + kc) ^ (row & 7)) << 3);
                bfr[ni] = *(const bf16x8*)&B_s[row * 64 + c];
            }
#pragma unroll
            for (int mi = 0; mi < 4; ++mi)
#pragma unroll
                for (int ni = 0; ni < 4; ++ni)
                    acc[mi][ni] = __builtin_amdgcn_mfma_f32_16x16x32_bf16(
                        af[mi], bfr[ni], acc[mi][ni], 0, 0, 0);
        }
    }

    // epilogue: C row = (lane>>4)*4+reg, col = lane&15 within each 16x16 tile
#pragma unroll
    for (int mi = 0; mi < 4; ++mi) {
        int rb = wm * 64 + mi * 16 + (lane >> 4) * 4;
#pragma unroll
        for (int reg = 0; reg < 4; ++reg) {
            int r = rb + reg;
            if (m0 + r < cnt) {
                size_t tok = (size_t)tok_s[r];
                float w = w_s[r];
                float* yrow = out + tok * DDIM + n0;
#pragma unroll
                for (int ni = 0; ni < 4; ++ni) {
                    int col = wn * 64 + ni * 16 + lm;
                    float v = w * (acc[mi][ni][reg] + bias_s[col]);
                    if (accum) v += yrow[col];
                    yrow[col] = v;
                }
            }
        }
    }
}

extern "C" void kernel_launch(void* const* d_in, const int* in_sizes, int n_in,
                              void* d_out, int out_size, void* d_ws, size_t ws_size,
                              hipStream_t stream) {
    const float* x     = (const float*)d_in[0];
    const float* noise = (const float*)d_in[1];
    const float* Wr    = (const float*)d_in[2];
    const float* br    = (const float*)d_in[3];
    const float* gamma = (const float*)d_in[4];
    const float* beta  = (const float*)d_in[5];
    const float* Wexp  = (const float*)d_in[6];
    const float* bexp  = (const float*)d_in[7];
    float* out = (float*)d_out;

    unsigned char* ws = (unsigned char*)d_ws;
    u16* WT       = (u16*)ws;                               // 16 MiB
    int* counts   = (int*)(ws + 16777216);                  // 64 B
    int* list_tok = (int*)(ws + 16777472);                  // 512 KiB
    float* list_w = (float*)(ws + 17301760);                // 512 KiB
    int* e01      = (int*)(ws + 17826048);                  // 32 KiB
    float2* w01   = (float2*)(ws + 17858816);               // 64 KiB
    u16* xb       = (u16*)(ws + 17924352);                  // 16 MiB (optional)
    const size_t need_bf16a = 17924352 + 16777216;          // ~33.1 MiB

    transpose_w<<<dim3(16, 16, 8), 256, 0, stream>>>(Wexp, WT);
    routing_compute<<<NTOK / 4, 256, 0, stream>>>(x, noise, Wr, br, gamma, beta,
                                                  e01, w01);
    build_lists<<<16, 256, 0, stream>>>(e01, w01, counts, list_tok, list_w);

    if (ws_size >= need_bf16a) {
        xcast<<<NTOK * DDIM / (256 * 8), 256, 0, stream>>>(x, xb);
        moe_gemm<1><<<dim3(4096), 256, 0, stream>>>(
            x, xb, WT, bexp, counts, list_tok, list_w, out, 0, 0);
        moe_gemm<1><<<dim3(4096), 256, 0, stream>>>(
            x, xb, WT, bexp, counts, list_tok, list_w, out, 8, 1);
    } else {
        moe_gemm<0><<<dim3(4096), 256, 0, stream>>>(
            x, xb, WT, bexp, counts, list_tok, list_w, out, 0, 0);
        moe_gemm<0><<<dim3(4096), 256, 0, stream>>>(
            x, xb, WT, bexp, counts, list_tok, list_w, out, 8, 1);
    }
}